// Round 2
// baseline (16575.854 us; speedup 1.0000x reference)
//
#include <hip/hip_runtime.h>
#include <cstddef>

// Problem constants
constexpr int B = 8;
constexpr int N = 16384;
constexpr int P = 1024;       // NPOINT
constexpr int S = 32;         // MAX_SAMPLES
constexpr int NSAMP = B * P * S;   // 262144
constexpr float EPS = 1e-5f;
constexpr float INV_N = 1.0f / 262144.0f;

// Workspace layout (bytes)
//   [0 .. 1048576)          gidx   (B*P*S int32)
//   [1048576 .. +4096)      stats  (float[992] used)
constexpr int ST_S1   = 0;    // 9   input sums
constexpr int ST_S2   = 9;    // 81  input second moments (full 9x9)
constexpr int ST_SUM1 = 96;   // 64  layer1 sum
constexpr int ST_SQ1  = 160;  // 64  layer1 sumsq
constexpr int ST_SUM2 = 224;  // 128 layer2 sum
constexpr int ST_SQ2  = 352;  // 128 layer2 sumsq
constexpr int ST_SC0  = 480;  // 64
constexpr int ST_SH0  = 544;  // 64
constexpr int ST_SC1  = 608;  // 64
constexpr int ST_SH1  = 672;  // 64
constexpr int ST_SC2  = 736;  // 128
constexpr int ST_SH2  = 864;  // 128

// ---------------------------------------------------------------------------
// 1) Farthest point sampling: one block per batch, 512 threads, 32 pts/thread.
//    launch_bounds(512,2) -> 256-VGPR budget so px/py/pz/dist (128 VGPRs)
//    stay in registers (round-0 had VGPR_Count=48 => all arrays spilled).
//    Argmax via u64 key = (distbits<<32)|(16383-idx): dists>=0 so IEEE bit
//    ordering == value ordering; low bits give first-index tie-break.
//    Winning point's coords travel through LDS (no dependent global load).
//    contract(off): must match numpy mul/add rounding — argmax flips cascade.
// ---------------------------------------------------------------------------
__global__ __launch_bounds__(512, 2) void fps_kernel(
    const float* __restrict__ xyz, float* __restrict__ cent) {
#pragma clang fp contract(off)
  const int b = blockIdx.x;
  const int t = threadIdx.x;           // 0..511
  const int wave = t >> 6;             // 0..7
  const float* X = xyz + (size_t)b * N * 3;

  float px[32], py[32], pz[32], dist[32];
#pragma unroll
  for (int k = 0; k < 32; k++) {
    int i = t + k * 512;
    px[k] = X[3 * i + 0];
    py[k] = X[3 * i + 1];
    pz[k] = X[3 * i + 2];
    dist[k] = 1e10f;
  }

  __shared__ unsigned long long skey[2][8];
  __shared__ float4 scoord[2][8];

  // initial centroid: index 0
  float cx = X[0], cy = X[1], cz = X[2];

  for (int j = 0; j < P; j++) {
    if (t == 0) {
      float* co = cent + ((size_t)b * P + j) * 3;
      co[0] = cx; co[1] = cy; co[2] = cz;
    }
    float best = -1.0f;
    int bk = 0;
#pragma unroll
    for (int k = 0; k < 32; k++) {
      float dx = px[k] - cx;
      float dy = py[k] - cy;
      float dz = pz[k] - cz;
      float d = (dx * dx + dy * dy) + dz * dz;   // match np: mul,add order
      float nd = fminf(dist[k], d);
      dist[k] = nd;
      if (nd > best) { best = nd; bk = k; }      // ascending idx in k
    }
    const int bi = t + bk * 512;
    unsigned long long key =
        ((unsigned long long)__float_as_uint(best) << 32) |
        (unsigned)(16383 - bi);
    // wave butterfly max (tie -> larger low bits = smaller index)
#pragma unroll
    for (int m = 1; m < 64; m <<= 1) {
      unsigned long long ok = __shfl_xor(key, m, 64);
      if (ok > key) key = ok;
    }
    const int buf = j & 1;
    // owner thread of the wave-winning point writes key + its coords
    const int wi = 16383 - (int)(unsigned)(key & 0xFFFFFFFFull);
    if (t == (wi & 511)) {
      const int k = wi >> 9;
      skey[buf][wave] = key;
      scoord[buf][wave] = make_float4(px[k], py[k], pz[k], 0.0f);
    }
    __syncthreads();
    // every thread redundantly reduces 8 entries (broadcast LDS reads)
    unsigned long long bkey = skey[buf][0];
    int bw = 0;
#pragma unroll
    for (int w = 1; w < 8; w++) {
      unsigned long long kk = skey[buf][w];
      if (kk > bkey) { bkey = kk; bw = w; }  // exact key ties impossible
    }
    float4 c4 = scoord[buf][bw];
    cx = c4.x; cy = c4.y; cz = c4.z;
  }
}

// ---------------------------------------------------------------------------
// 2) Ball query: one wave per centroid; first <=32 in-radius indices ascending.
// ---------------------------------------------------------------------------
__global__ __launch_bounds__(256) void ballq_kernel(
    const float* __restrict__ xyz, const float* __restrict__ cent,
    int* __restrict__ gidx) {
#pragma clang fp contract(off)
  const int wid = (blockIdx.x * 256 + threadIdx.x) >> 6;   // 0..8191 (b*P+p)
  const int lane = threadIdx.x & 63;
  const int b = wid >> 10;
  const float* X = xyz + (size_t)b * N * 3;
  const float* c = cent + (size_t)wid * 3;
  const float cx = c[0], cy = c[1], cz = c[2];
  const float cc = (cx * cx + cy * cy) + cz * cz;
  int* g = gidx + (size_t)wid * S;
  const float r2 = 0.2f * 0.2f;

  int cnt = 0;
  for (int base = 0; base < N; base += 64) {
    const int i = base + lane;
    float x = X[3 * i + 0], y = X[3 * i + 1], z = X[3 * i + 2];
    float xx = (x * x + y * y) + z * z;
    float dt = (cx * x + cy * y) + cz * z;
    float d2 = (cc - 2.0f * dt) + xx;            // match reference expanded form
    bool inr = d2 < r2;
    unsigned long long m = __ballot(inr);
    if (inr) {
      int pos = cnt + (int)__popcll(m & ((1ull << lane) - 1ull));
      if (pos < S) g[pos] = i;
    }
    cnt += (int)__popcll(m);
    if (cnt >= S) break;                          // uniform early exit
  }
}

// ---------------------------------------------------------------------------
// Gather one sample's 9 input channels (grouped_xyz - centroid, grouped_pts)
// ---------------------------------------------------------------------------
__device__ __forceinline__ void load_x(
    const float* __restrict__ xyz, const float* __restrict__ points,
    const float* __restrict__ cent, const int* __restrict__ gidx,
    int sample, float x[9]) {
  const int grp = sample >> 5;          // b*P+p
  const int b = grp >> 10;
  const int idx = gidx[sample];
  const float* Xp = xyz + ((size_t)b * N + idx) * 3;
  const float* Pp = points + ((size_t)b * N + idx) * 6;
  const float* C = cent + (size_t)grp * 3;
  x[0] = Xp[0] - C[0];
  x[1] = Xp[1] - C[1];
  x[2] = Xp[2] - C[2];
  x[3] = Pp[0]; x[4] = Pp[1]; x[5] = Pp[2];
  x[6] = Pp[3]; x[7] = Pp[4]; x[8] = Pp[5];
}

// ---------------------------------------------------------------------------
// 3) Input moments (Sum x, Sum x x^T) -> exact layer-0 BN stats analytically.
// ---------------------------------------------------------------------------
__global__ __launch_bounds__(256) void moments_kernel(
    const float* __restrict__ xyz, const float* __restrict__ points,
    const float* __restrict__ cent, const int* __restrict__ gidx,
    float* __restrict__ stats) {
  const int tid = blockIdx.x * 256 + threadIdx.x;   // 8192 threads
  float S1[9], S2[81];
#pragma unroll
  for (int c = 0; c < 9; c++) S1[c] = 0.f;
#pragma unroll
  for (int k = 0; k < 81; k++) S2[k] = 0.f;

  for (int smp = tid; smp < NSAMP; smp += 8192) {
    float x[9];
    load_x(xyz, points, cent, gidx, smp, x);
#pragma unroll
    for (int c = 0; c < 9; c++) {
      S1[c] += x[c];
#pragma unroll
      for (int d = 0; d < 9; d++) S2[c * 9 + d] = fmaf(x[c], x[d], S2[c * 9 + d]);
    }
  }
  const int lane = threadIdx.x & 63;
#pragma unroll
  for (int c = 0; c < 9; c++) {
#pragma unroll
    for (int m = 1; m < 64; m <<= 1) S1[c] += __shfl_xor(S1[c], m, 64);
  }
#pragma unroll
  for (int k = 0; k < 81; k++) {
#pragma unroll
    for (int m = 1; m < 64; m <<= 1) S2[k] += __shfl_xor(S2[k], m, 64);
  }
  if (lane == 0) {
#pragma unroll
    for (int c = 0; c < 9; c++) atomicAdd(&stats[ST_S1 + c], S1[c]);
#pragma unroll
    for (int k = 0; k < 81; k++) atomicAdd(&stats[ST_S2 + k], S2[k]);
  }
}

__global__ void finalize0_kernel(float* __restrict__ stats,
                                 const float* __restrict__ w0,
                                 const float* __restrict__ b0,
                                 const float* __restrict__ g0,
                                 const float* __restrict__ be0) {
  const int o = threadIdx.x;   // 64
  float w[9];
#pragma unroll
  for (int c = 0; c < 9; c++) w[c] = w0[o * 9 + c];
  float dot = 0.f;
#pragma unroll
  for (int c = 0; c < 9; c++) dot += w[c] * stats[ST_S1 + c];
  float quad = 0.f;
#pragma unroll
  for (int c = 0; c < 9; c++)
#pragma unroll
    for (int d = 0; d < 9; d++) quad += w[c] * w[d] * stats[ST_S2 + c * 9 + d];
  const float bb = b0[o];
  const float mean = dot * INV_N + bb;
  const float Ey2 = (quad + 2.0f * bb * dot) * INV_N + bb * bb;
  const float var = Ey2 - mean * mean;
  const float sc = g0[o] / sqrtf(var + EPS);
  stats[ST_SC0 + o] = sc;
  stats[ST_SH0 + o] = be0[o] - mean * sc;
}

// ---------------------------------------------------------------------------
// h0 / h1 recompute helpers (fully unrolled: arrays must stay in registers)
// ---------------------------------------------------------------------------
__device__ __forceinline__ void compute_h0(
    const float x[9], const float* __restrict__ w0, const float* __restrict__ b0,
    const float* __restrict__ stats, float h0[64]) {
  const float* sc = stats + ST_SC0;
  const float* sh = stats + ST_SH0;
#pragma unroll
  for (int o = 0; o < 64; o++) {
    float a = b0[o];
#pragma unroll
    for (int c = 0; c < 9; c++) a = fmaf(w0[o * 9 + c], x[c], a);
    h0[o] = fmaxf(fmaf(a, sc[o], sh[o]), 0.0f);
  }
}

__device__ __forceinline__ void compute_h1(
    const float h0[64], const float* __restrict__ w1, const float* __restrict__ b1,
    const float* __restrict__ stats, float h1[64]) {
  const float* sc = stats + ST_SC1;
  const float* sh = stats + ST_SH1;
#pragma unroll
  for (int o = 0; o < 64; o++) {
    float a = b1[o];
#pragma unroll
    for (int c = 0; c < 64; c++) a = fmaf(w1[o * 64 + c], h0[c], a);
    h1[o] = fmaxf(fmaf(a, sc[o], sh[o]), 0.0f);
  }
}

// ---------------------------------------------------------------------------
// 4) Layer-1 pre-BN stats: recompute h0, accumulate per-channel sum/sumsq.
// ---------------------------------------------------------------------------
__global__ __launch_bounds__(256) void pass2_kernel(
    const float* __restrict__ xyz, const float* __restrict__ points,
    const float* __restrict__ cent, const int* __restrict__ gidx,
    const float* __restrict__ w0, const float* __restrict__ b0,
    const float* __restrict__ w1, const float* __restrict__ b1,
    float* __restrict__ stats) {
  const int tid = blockIdx.x * 256 + threadIdx.x;
  float x[9];
  load_x(xyz, points, cent, gidx, tid, x);
  float h0[64];
  compute_h0(x, w0, b0, stats, h0);

  __shared__ float ssum[4][64], ssq[4][64];
  const int wv = threadIdx.x >> 6, lane = threadIdx.x & 63;
#pragma unroll 1
  for (int o = 0; o < 64; o++) {
    float a = b1[o];
#pragma unroll
    for (int c = 0; c < 64; c++) a = fmaf(w1[o * 64 + c], h0[c], a);
    float s = a, q = a * a;
#pragma unroll
    for (int m = 1; m < 64; m <<= 1) {
      s += __shfl_xor(s, m, 64);
      q += __shfl_xor(q, m, 64);
    }
    if (lane == 0) { ssum[wv][o] = s; ssq[wv][o] = q; }
  }
  __syncthreads();
  if (threadIdx.x < 64) {
    const int o = threadIdx.x;
    float s = ssum[0][o] + ssum[1][o] + ssum[2][o] + ssum[3][o];
    float q = ssq[0][o] + ssq[1][o] + ssq[2][o] + ssq[3][o];
    atomicAdd(&stats[ST_SUM1 + o], s);
    atomicAdd(&stats[ST_SQ1 + o], q);
  }
}

__global__ void finalize1_kernel(float* __restrict__ stats,
                                 const float* __restrict__ g1,
                                 const float* __restrict__ be1) {
  const int o = threadIdx.x;   // 64
  const float mean = stats[ST_SUM1 + o] * INV_N;
  const float var = stats[ST_SQ1 + o] * INV_N - mean * mean;
  const float sc = g1[o] / sqrtf(var + EPS);
  stats[ST_SC1 + o] = sc;
  stats[ST_SH1 + o] = be1[o] - mean * sc;
}

// ---------------------------------------------------------------------------
// 5) Layer-2 pre-BN stats: recompute h0,h1, accumulate 128-channel sum/sumsq.
// ---------------------------------------------------------------------------
__global__ __launch_bounds__(256) void pass3_kernel(
    const float* __restrict__ xyz, const float* __restrict__ points,
    const float* __restrict__ cent, const int* __restrict__ gidx,
    const float* __restrict__ w0, const float* __restrict__ b0,
    const float* __restrict__ w1, const float* __restrict__ b1,
    const float* __restrict__ w2, const float* __restrict__ b2,
    float* __restrict__ stats) {
  const int tid = blockIdx.x * 256 + threadIdx.x;
  float x[9];
  load_x(xyz, points, cent, gidx, tid, x);
  float h0[64];
  compute_h0(x, w0, b0, stats, h0);
  float h1[64];
  compute_h1(h0, w1, b1, stats, h1);

  __shared__ float ssum[4][128], ssq[4][128];
  const int wv = threadIdx.x >> 6, lane = threadIdx.x & 63;
#pragma unroll 1
  for (int o = 0; o < 128; o++) {
    float a = b2[o];
#pragma unroll
    for (int c = 0; c < 64; c++) a = fmaf(w2[o * 64 + c], h1[c], a);
    float s = a, q = a * a;
#pragma unroll
    for (int m = 1; m < 64; m <<= 1) {
      s += __shfl_xor(s, m, 64);
      q += __shfl_xor(q, m, 64);
    }
    if (lane == 0) { ssum[wv][o] = s; ssq[wv][o] = q; }
  }
  __syncthreads();
  if (threadIdx.x < 128) {
    const int o = threadIdx.x;
    float s = ssum[0][o] + ssum[1][o] + ssum[2][o] + ssum[3][o];
    float q = ssq[0][o] + ssq[1][o] + ssq[2][o] + ssq[3][o];
    atomicAdd(&stats[ST_SUM2 + o], s);
    atomicAdd(&stats[ST_SQ2 + o], q);
  }
}

__global__ void finalize2_kernel(float* __restrict__ stats,
                                 const float* __restrict__ g2,
                                 const float* __restrict__ be2) {
  const int o = threadIdx.x;   // 128
  const float mean = stats[ST_SUM2 + o] * INV_N;
  const float var = stats[ST_SQ2 + o] * INV_N - mean * mean;
  const float sc = g2[o] / sqrtf(var + EPS);
  stats[ST_SC2 + o] = sc;
  stats[ST_SH2 + o] = be2[o] - mean * sc;
}

// ---------------------------------------------------------------------------
// 6) Final pass: recompute chain, BN2+ReLU, max over S via half-wave shuffles.
// ---------------------------------------------------------------------------
__global__ __launch_bounds__(256) void pass4_kernel(
    const float* __restrict__ xyz, const float* __restrict__ points,
    const float* __restrict__ cent, const int* __restrict__ gidx,
    const float* __restrict__ w0, const float* __restrict__ b0,
    const float* __restrict__ w1, const float* __restrict__ b1,
    const float* __restrict__ w2, const float* __restrict__ b2,
    const float* __restrict__ stats, float* __restrict__ outnp) {
  const int wid = (blockIdx.x * 256 + threadIdx.x) >> 6;  // 0..4095
  const int lane = threadIdx.x & 63;
  const int grp = wid * 2 + (lane >> 5);                  // 0..8191
  const int s = lane & 31;
  const int sample = grp * 32 + s;

  float x[9];
  load_x(xyz, points, cent, gidx, sample, x);
  float h0[64];
  compute_h0(x, w0, b0, stats, h0);
  float h1[64];
  compute_h1(h0, w1, b1, stats, h1);

  const float* sc2 = stats + ST_SC2;
  const float* sh2 = stats + ST_SH2;
#pragma unroll 1
  for (int o = 0; o < 128; o++) {
    float a = b2[o];
#pragma unroll
    for (int c = 0; c < 64; c++) a = fmaf(w2[o * 64 + c], h1[c], a);
    float v = fmaxf(fmaf(a, sc2[o], sh2[o]), 0.0f);
#pragma unroll
    for (int m = 1; m < 32; m <<= 1) v = fmaxf(v, __shfl_xor(v, m, 64));
    if ((lane & 31) == 0) outnp[(size_t)grp * 128 + o] = v;
  }
}

// ---------------------------------------------------------------------------
extern "C" void kernel_launch(void* const* d_in, const int* in_sizes, int n_in,
                              void* d_out, int out_size, void* d_ws,
                              size_t ws_size, hipStream_t stream) {
  const float* xyz = (const float*)d_in[0];
  const float* points = (const float*)d_in[1];
  const float* w0 = (const float*)d_in[2];
  const float* b0 = (const float*)d_in[3];
  const float* g0 = (const float*)d_in[4];
  const float* be0 = (const float*)d_in[5];
  const float* w1 = (const float*)d_in[6];
  const float* b1 = (const float*)d_in[7];
  const float* g1 = (const float*)d_in[8];
  const float* be1 = (const float*)d_in[9];
  const float* w2 = (const float*)d_in[10];
  const float* b2 = (const float*)d_in[11];
  const float* g2 = (const float*)d_in[12];
  const float* be2 = (const float*)d_in[13];

  float* out = (float*)d_out;
  float* cent = out;                    // (B,P,3)
  float* outnp = out + B * P * 3;       // (B,P,128)

  const size_t GIDX_BYTES = (size_t)NSAMP * sizeof(int);      // 1 MiB
  const size_t STATS_BYTES = 4096;
  if (ws_size < GIDX_BYTES + STATS_BYTES) return;             // defensive
  int* gidx = (int*)d_ws;
  float* stats = (float*)((char*)d_ws + GIDX_BYTES);

  hipMemsetAsync(d_ws, 0, GIDX_BYTES + STATS_BYTES, stream);

  fps_kernel<<<B, 512, 0, stream>>>(xyz, cent);
  ballq_kernel<<<(B * P) / 4, 256, 0, stream>>>(xyz, cent, gidx);
  moments_kernel<<<32, 256, 0, stream>>>(xyz, points, cent, gidx, stats);
  finalize0_kernel<<<1, 64, 0, stream>>>(stats, w0, b0, g0, be0);
  pass2_kernel<<<NSAMP / 256, 256, 0, stream>>>(xyz, points, cent, gidx,
                                                w0, b0, w1, b1, stats);
  finalize1_kernel<<<1, 64, 0, stream>>>(stats, g1, be1);
  pass3_kernel<<<NSAMP / 256, 256, 0, stream>>>(xyz, points, cent, gidx,
                                                w0, b0, w1, b1, w2, b2, stats);
  finalize2_kernel<<<1, 128, 0, stream>>>(stats, g2, be2);
  pass4_kernel<<<NSAMP / 256, 256, 0, stream>>>(xyz, points, cent, gidx,
                                                w0, b0, w1, b1, w2, b2, stats,
                                                outnp);
}

// Round 3
// 2465.529 us; speedup vs baseline: 6.7230x; 6.7230x over previous
//
#include <hip/hip_runtime.h>
#include <cstddef>

// Problem constants
constexpr int B = 8;
constexpr int N = 16384;
constexpr int P = 1024;       // NPOINT
constexpr int S = 32;         // MAX_SAMPLES
constexpr int NSAMP = B * P * S;   // 262144
constexpr float EPS = 1e-5f;
constexpr float INV_N = 1.0f / 262144.0f;

typedef float v2f __attribute__((ext_vector_type(2)));

// Workspace layout (bytes)
//   [0 .. 1048576)          gidx   (B*P*S int32)
//   [1048576 .. +4096)      stats  (float[992] used)
constexpr int ST_S1   = 0;    // 9   input sums
constexpr int ST_S2   = 9;    // 81  input second moments (full 9x9)
constexpr int ST_SUM1 = 96;   // 64  layer1 sum
constexpr int ST_SQ1  = 160;  // 64  layer1 sumsq
constexpr int ST_SUM2 = 224;  // 128 layer2 sum
constexpr int ST_SQ2  = 352;  // 128 layer2 sumsq
constexpr int ST_SC0  = 480;  // 64
constexpr int ST_SH0  = 544;  // 64
constexpr int ST_SC1  = 608;  // 64
constexpr int ST_SH1  = 672;  // 64
constexpr int ST_SC2  = 736;  // 128
constexpr int ST_SH2  = 864;  // 128

// ---------------------------------------------------------------------------
// 1) Farthest point sampling: one block per batch, 512 threads, 32 pts/thread
//    stored as float2[16] per coord (v_pk_*_f32 path). 128 array VGPRs stay
//    in registers under __launch_bounds__(512,2) (256-VGPR cap).
//    RULE (round-2 lesson): register arrays use COMPILE-TIME indices only —
//    any runtime index demotes the array to scratch (15.9ms regression).
//    Winner coords re-fetched via uniform global load (L2-hit, ~200cyc).
//    Argmax key u64 = (distbits<<32)|(16383-idx): dists>=0 so IEEE bit order
//    == value order; low bits give first-index tie-break.
//    contract(off): must match numpy mul/add rounding — argmax flips cascade.
// ---------------------------------------------------------------------------
__global__ __launch_bounds__(512, 2) void fps_kernel(
    const float* __restrict__ xyz, float* __restrict__ cent) {
#pragma clang fp contract(off)
  const int b = blockIdx.x;
  const int t = threadIdx.x;           // 0..511
  const int wave = t >> 6;             // 0..7
  const float* X = xyz + (size_t)b * N * 3;

  // element e of pair m <-> k = 2m+e <-> point index t + k*512
  v2f px[16], py[16], pz[16], dist[16];
#pragma unroll
  for (int m = 0; m < 16; m++) {
    int i0 = t + (2 * m) * 512;
    int i1 = t + (2 * m + 1) * 512;
    px[m] = (v2f){X[3 * i0 + 0], X[3 * i1 + 0]};
    py[m] = (v2f){X[3 * i0 + 1], X[3 * i1 + 1]};
    pz[m] = (v2f){X[3 * i0 + 2], X[3 * i1 + 2]};
    dist[m] = (v2f){1e10f, 1e10f};
  }

  __shared__ unsigned long long skey[2][8];

  float cx = X[0], cy = X[1], cz = X[2];   // start index 0

  for (int j = 0; j < P; j++) {
    if (t == 0) {
      float* co = cent + ((size_t)b * P + j) * 3;
      co[0] = cx; co[1] = cy; co[2] = cz;
    }
    const v2f cx2 = (v2f){cx, cx};
    const v2f cy2 = (v2f){cy, cy};
    const v2f cz2 = (v2f){cz, cz};
    float best = -1.0f;
    int bk = 0;
#pragma unroll
    for (int m = 0; m < 16; m++) {
      v2f dx = px[m] - cx2;
      v2f dy = py[m] - cy2;
      v2f dz = pz[m] - cz2;
      v2f d = (dx * dx + dy * dy) + dz * dz;   // elementwise, np rounding
      v2f nd;
      nd.x = fminf(dist[m].x, d.x);
      nd.y = fminf(dist[m].y, d.y);
      dist[m] = nd;
      if (nd.x > best) { best = nd.x; bk = 2 * m; }      // ascending k order
      if (nd.y > best) { best = nd.y; bk = 2 * m + 1; }
    }
    const int bi = t + bk * 512;
    unsigned long long key =
        ((unsigned long long)__float_as_uint(best) << 32) |
        (unsigned)(16383 - bi);
#pragma unroll
    for (int m = 1; m < 64; m <<= 1) {
      unsigned long long ok = __shfl_xor(key, m, 64);
      if (ok > key) key = ok;
    }
    const int buf = j & 1;
    if ((t & 63) == 0) skey[buf][wave] = key;
    __syncthreads();
    unsigned long long bkey = skey[buf][0];
#pragma unroll
    for (int w = 1; w < 8; w++) {
      unsigned long long kk = skey[buf][w];
      if (kk > bkey) bkey = kk;
    }
    const int wi = 16383 - (int)(unsigned)(bkey & 0xFFFFFFFFull);
    // uniform broadcast load of next centroid's coords (L1/L2 hit)
    cx = X[3 * wi + 0];
    cy = X[3 * wi + 1];
    cz = X[3 * wi + 2];
  }
}

// ---------------------------------------------------------------------------
// 2) Ball query: one wave per centroid; first <=32 in-radius indices ascending.
// ---------------------------------------------------------------------------
__global__ __launch_bounds__(256) void ballq_kernel(
    const float* __restrict__ xyz, const float* __restrict__ cent,
    int* __restrict__ gidx) {
#pragma clang fp contract(off)
  const int wid = (blockIdx.x * 256 + threadIdx.x) >> 6;   // 0..8191 (b*P+p)
  const int lane = threadIdx.x & 63;
  const int b = wid >> 10;
  const float* X = xyz + (size_t)b * N * 3;
  const float* c = cent + (size_t)wid * 3;
  const float cx = c[0], cy = c[1], cz = c[2];
  const float cc = (cx * cx + cy * cy) + cz * cz;
  int* g = gidx + (size_t)wid * S;
  const float r2 = 0.2f * 0.2f;

  int cnt = 0;
  for (int base = 0; base < N; base += 64) {
    const int i = base + lane;
    float x = X[3 * i + 0], y = X[3 * i + 1], z = X[3 * i + 2];
    float xx = (x * x + y * y) + z * z;
    float dt = (cx * x + cy * y) + cz * z;
    float d2 = (cc - 2.0f * dt) + xx;            // match reference expanded form
    bool inr = d2 < r2;
    unsigned long long m = __ballot(inr);
    if (inr) {
      int pos = cnt + (int)__popcll(m & ((1ull << lane) - 1ull));
      if (pos < S) g[pos] = i;
    }
    cnt += (int)__popcll(m);
    if (cnt >= S) break;                          // uniform early exit
  }
}

// ---------------------------------------------------------------------------
// Gather one sample's 9 input channels (grouped_xyz - centroid, grouped_pts)
// ---------------------------------------------------------------------------
__device__ __forceinline__ void load_x(
    const float* __restrict__ xyz, const float* __restrict__ points,
    const float* __restrict__ cent, const int* __restrict__ gidx,
    int sample, float x[9]) {
  const int grp = sample >> 5;          // b*P+p
  const int b = grp >> 10;
  const int idx = gidx[sample];
  const float* Xp = xyz + ((size_t)b * N + idx) * 3;
  const float* Pp = points + ((size_t)b * N + idx) * 6;
  const float* C = cent + (size_t)grp * 3;
  x[0] = Xp[0] - C[0];
  x[1] = Xp[1] - C[1];
  x[2] = Xp[2] - C[2];
  x[3] = Pp[0]; x[4] = Pp[1]; x[5] = Pp[2];
  x[6] = Pp[3]; x[7] = Pp[4]; x[8] = Pp[5];
}

// ---------------------------------------------------------------------------
// 3) Input moments (Sum x, Sum x x^T) -> exact layer-0 BN stats analytically.
// ---------------------------------------------------------------------------
__global__ __launch_bounds__(256) void moments_kernel(
    const float* __restrict__ xyz, const float* __restrict__ points,
    const float* __restrict__ cent, const int* __restrict__ gidx,
    float* __restrict__ stats) {
  const int tid = blockIdx.x * 256 + threadIdx.x;   // 8192 threads
  float S1[9], S2[81];
#pragma unroll
  for (int c = 0; c < 9; c++) S1[c] = 0.f;
#pragma unroll
  for (int k = 0; k < 81; k++) S2[k] = 0.f;

  for (int smp = tid; smp < NSAMP; smp += 8192) {
    float x[9];
    load_x(xyz, points, cent, gidx, smp, x);
#pragma unroll
    for (int c = 0; c < 9; c++) {
      S1[c] += x[c];
#pragma unroll
      for (int d = 0; d < 9; d++) S2[c * 9 + d] = fmaf(x[c], x[d], S2[c * 9 + d]);
    }
  }
  const int lane = threadIdx.x & 63;
#pragma unroll
  for (int c = 0; c < 9; c++) {
#pragma unroll
    for (int m = 1; m < 64; m <<= 1) S1[c] += __shfl_xor(S1[c], m, 64);
  }
#pragma unroll
  for (int k = 0; k < 81; k++) {
#pragma unroll
    for (int m = 1; m < 64; m <<= 1) S2[k] += __shfl_xor(S2[k], m, 64);
  }
  if (lane == 0) {
#pragma unroll
    for (int c = 0; c < 9; c++) atomicAdd(&stats[ST_S1 + c], S1[c]);
#pragma unroll
    for (int k = 0; k < 81; k++) atomicAdd(&stats[ST_S2 + k], S2[k]);
  }
}

__global__ void finalize0_kernel(float* __restrict__ stats,
                                 const float* __restrict__ w0,
                                 const float* __restrict__ b0,
                                 const float* __restrict__ g0,
                                 const float* __restrict__ be0) {
  const int o = threadIdx.x;   // 64
  float w[9];
#pragma unroll
  for (int c = 0; c < 9; c++) w[c] = w0[o * 9 + c];
  float dot = 0.f;
#pragma unroll
  for (int c = 0; c < 9; c++) dot += w[c] * stats[ST_S1 + c];
  float quad = 0.f;
#pragma unroll
  for (int c = 0; c < 9; c++)
#pragma unroll
    for (int d = 0; d < 9; d++) quad += w[c] * w[d] * stats[ST_S2 + c * 9 + d];
  const float bb = b0[o];
  const float mean = dot * INV_N + bb;
  const float Ey2 = (quad + 2.0f * bb * dot) * INV_N + bb * bb;
  const float var = Ey2 - mean * mean;
  const float sc = g0[o] / sqrtf(var + EPS);
  stats[ST_SC0 + o] = sc;
  stats[ST_SH0 + o] = be0[o] - mean * sc;
}

// ---------------------------------------------------------------------------
// h0 / h1 recompute helpers (fully unrolled: arrays must stay in registers)
// ---------------------------------------------------------------------------
__device__ __forceinline__ void compute_h0(
    const float x[9], const float* __restrict__ w0, const float* __restrict__ b0,
    const float* __restrict__ stats, float h0[64]) {
  const float* sc = stats + ST_SC0;
  const float* sh = stats + ST_SH0;
#pragma unroll
  for (int o = 0; o < 64; o++) {
    float a = b0[o];
#pragma unroll
    for (int c = 0; c < 9; c++) a = fmaf(w0[o * 9 + c], x[c], a);
    h0[o] = fmaxf(fmaf(a, sc[o], sh[o]), 0.0f);
  }
}

__device__ __forceinline__ void compute_h1(
    const float h0[64], const float* __restrict__ w1, const float* __restrict__ b1,
    const float* __restrict__ stats, float h1[64]) {
  const float* sc = stats + ST_SC1;
  const float* sh = stats + ST_SH1;
#pragma unroll
  for (int o = 0; o < 64; o++) {
    float a = b1[o];
#pragma unroll
    for (int c = 0; c < 64; c++) a = fmaf(w1[o * 64 + c], h0[c], a);
    h1[o] = fmaxf(fmaf(a, sc[o], sh[o]), 0.0f);
  }
}

// ---------------------------------------------------------------------------
// 4) Layer-1 pre-BN stats: recompute h0, accumulate per-channel sum/sumsq.
// ---------------------------------------------------------------------------
__global__ __launch_bounds__(256) void pass2_kernel(
    const float* __restrict__ xyz, const float* __restrict__ points,
    const float* __restrict__ cent, const int* __restrict__ gidx,
    const float* __restrict__ w0, const float* __restrict__ b0,
    const float* __restrict__ w1, const float* __restrict__ b1,
    float* __restrict__ stats) {
  const int tid = blockIdx.x * 256 + threadIdx.x;
  float x[9];
  load_x(xyz, points, cent, gidx, tid, x);
  float h0[64];
  compute_h0(x, w0, b0, stats, h0);

  __shared__ float ssum[4][64], ssq[4][64];
  const int wv = threadIdx.x >> 6, lane = threadIdx.x & 63;
#pragma unroll 1
  for (int o = 0; o < 64; o++) {
    float a = b1[o];
#pragma unroll
    for (int c = 0; c < 64; c++) a = fmaf(w1[o * 64 + c], h0[c], a);
    float s = a, q = a * a;
#pragma unroll
    for (int m = 1; m < 64; m <<= 1) {
      s += __shfl_xor(s, m, 64);
      q += __shfl_xor(q, m, 64);
    }
    if (lane == 0) { ssum[wv][o] = s; ssq[wv][o] = q; }
  }
  __syncthreads();
  if (threadIdx.x < 64) {
    const int o = threadIdx.x;
    float s = ssum[0][o] + ssum[1][o] + ssum[2][o] + ssum[3][o];
    float q = ssq[0][o] + ssq[1][o] + ssq[2][o] + ssq[3][o];
    atomicAdd(&stats[ST_SUM1 + o], s);
    atomicAdd(&stats[ST_SQ1 + o], q);
  }
}

__global__ void finalize1_kernel(float* __restrict__ stats,
                                 const float* __restrict__ g1,
                                 const float* __restrict__ be1) {
  const int o = threadIdx.x;   // 64
  const float mean = stats[ST_SUM1 + o] * INV_N;
  const float var = stats[ST_SQ1 + o] * INV_N - mean * mean;
  const float sc = g1[o] / sqrtf(var + EPS);
  stats[ST_SC1 + o] = sc;
  stats[ST_SH1 + o] = be1[o] - mean * sc;
}

// ---------------------------------------------------------------------------
// 5) Layer-2 pre-BN stats: recompute h0,h1, accumulate 128-channel sum/sumsq.
// ---------------------------------------------------------------------------
__global__ __launch_bounds__(256) void pass3_kernel(
    const float* __restrict__ xyz, const float* __restrict__ points,
    const float* __restrict__ cent, const int* __restrict__ gidx,
    const float* __restrict__ w0, const float* __restrict__ b0,
    const float* __restrict__ w1, const float* __restrict__ b1,
    const float* __restrict__ w2, const float* __restrict__ b2,
    float* __restrict__ stats) {
  const int tid = blockIdx.x * 256 + threadIdx.x;
  float x[9];
  load_x(xyz, points, cent, gidx, tid, x);
  float h0[64];
  compute_h0(x, w0, b0, stats, h0);
  float h1[64];
  compute_h1(h0, w1, b1, stats, h1);

  __shared__ float ssum[4][128], ssq[4][128];
  const int wv = threadIdx.x >> 6, lane = threadIdx.x & 63;
#pragma unroll 1
  for (int o = 0; o < 128; o++) {
    float a = b2[o];
#pragma unroll
    for (int c = 0; c < 64; c++) a = fmaf(w2[o * 64 + c], h1[c], a);
    float s = a, q = a * a;
#pragma unroll
    for (int m = 1; m < 64; m <<= 1) {
      s += __shfl_xor(s, m, 64);
      q += __shfl_xor(q, m, 64);
    }
    if (lane == 0) { ssum[wv][o] = s; ssq[wv][o] = q; }
  }
  __syncthreads();
  if (threadIdx.x < 128) {
    const int o = threadIdx.x;
    float s = ssum[0][o] + ssum[1][o] + ssum[2][o] + ssum[3][o];
    float q = ssq[0][o] + ssq[1][o] + ssq[2][o] + ssq[3][o];
    atomicAdd(&stats[ST_SUM2 + o], s);
    atomicAdd(&stats[ST_SQ2 + o], q);
  }
}

__global__ void finalize2_kernel(float* __restrict__ stats,
                                 const float* __restrict__ g2,
                                 const float* __restrict__ be2) {
  const int o = threadIdx.x;   // 128
  const float mean = stats[ST_SUM2 + o] * INV_N;
  const float var = stats[ST_SQ2 + o] * INV_N - mean * mean;
  const float sc = g2[o] / sqrtf(var + EPS);
  stats[ST_SC2 + o] = sc;
  stats[ST_SH2 + o] = be2[o] - mean * sc;
}

// ---------------------------------------------------------------------------
// 6) Final pass: recompute chain, BN2+ReLU, max over S via half-wave shuffles.
// ---------------------------------------------------------------------------
__global__ __launch_bounds__(256) void pass4_kernel(
    const float* __restrict__ xyz, const float* __restrict__ points,
    const float* __restrict__ cent, const int* __restrict__ gidx,
    const float* __restrict__ w0, const float* __restrict__ b0,
    const float* __restrict__ w1, const float* __restrict__ b1,
    const float* __restrict__ w2, const float* __restrict__ b2,
    const float* __restrict__ stats, float* __restrict__ outnp) {
  const int wid = (blockIdx.x * 256 + threadIdx.x) >> 6;  // 0..4095
  const int lane = threadIdx.x & 63;
  const int grp = wid * 2 + (lane >> 5);                  // 0..8191
  const int s = lane & 31;
  const int sample = grp * 32 + s;

  float x[9];
  load_x(xyz, points, cent, gidx, sample, x);
  float h0[64];
  compute_h0(x, w0, b0, stats, h0);
  float h1[64];
  compute_h1(h0, w1, b1, stats, h1);

  const float* sc2 = stats + ST_SC2;
  const float* sh2 = stats + ST_SH2;
#pragma unroll 1
  for (int o = 0; o < 128; o++) {
    float a = b2[o];
#pragma unroll
    for (int c = 0; c < 64; c++) a = fmaf(w2[o * 64 + c], h1[c], a);
    float v = fmaxf(fmaf(a, sc2[o], sh2[o]), 0.0f);
#pragma unroll
    for (int m = 1; m < 32; m <<= 1) v = fmaxf(v, __shfl_xor(v, m, 64));
    if ((lane & 31) == 0) outnp[(size_t)grp * 128 + o] = v;
  }
}

// ---------------------------------------------------------------------------
extern "C" void kernel_launch(void* const* d_in, const int* in_sizes, int n_in,
                              void* d_out, int out_size, void* d_ws,
                              size_t ws_size, hipStream_t stream) {
  const float* xyz = (const float*)d_in[0];
  const float* points = (const float*)d_in[1];
  const float* w0 = (const float*)d_in[2];
  const float* b0 = (const float*)d_in[3];
  const float* g0 = (const float*)d_in[4];
  const float* be0 = (const float*)d_in[5];
  const float* w1 = (const float*)d_in[6];
  const float* b1 = (const float*)d_in[7];
  const float* g1 = (const float*)d_in[8];
  const float* be1 = (const float*)d_in[9];
  const float* w2 = (const float*)d_in[10];
  const float* b2 = (const float*)d_in[11];
  const float* g2 = (const float*)d_in[12];
  const float* be2 = (const float*)d_in[13];

  float* out = (float*)d_out;
  float* cent = out;                    // (B,P,3)
  float* outnp = out + B * P * 3;       // (B,P,128)

  const size_t GIDX_BYTES = (size_t)NSAMP * sizeof(int);      // 1 MiB
  const size_t STATS_BYTES = 4096;
  if (ws_size < GIDX_BYTES + STATS_BYTES) return;             // defensive
  int* gidx = (int*)d_ws;
  float* stats = (float*)((char*)d_ws + GIDX_BYTES);

  hipMemsetAsync(d_ws, 0, GIDX_BYTES + STATS_BYTES, stream);

  fps_kernel<<<B, 512, 0, stream>>>(xyz, cent);
  ballq_kernel<<<(B * P) / 4, 256, 0, stream>>>(xyz, cent, gidx);
  moments_kernel<<<32, 256, 0, stream>>>(xyz, points, cent, gidx, stats);
  finalize0_kernel<<<1, 64, 0, stream>>>(stats, w0, b0, g0, be0);
  pass2_kernel<<<NSAMP / 256, 256, 0, stream>>>(xyz, points, cent, gidx,
                                                w0, b0, w1, b1, stats);
  finalize1_kernel<<<1, 64, 0, stream>>>(stats, g1, be1);
  pass3_kernel<<<NSAMP / 256, 256, 0, stream>>>(xyz, points, cent, gidx,
                                                w0, b0, w1, b1, w2, b2, stats);
  finalize2_kernel<<<1, 128, 0, stream>>>(stats, g2, be2);
  pass4_kernel<<<NSAMP / 256, 256, 0, stream>>>(xyz, points, cent, gidx,
                                                w0, b0, w1, b1, w2, b2, stats,
                                                outnp);
}